// Round 1
// baseline (1432.690 us; speedup 1.0000x reference)
//
#include <hip/hip_runtime.h>

#define T_TOKENS 8192
#define DIM 1024
#define NEXP 8
#define HID 4096
#define ROWS (2 * T_TOKENS)       /* 16384 packed (token,expert) rows */
#define ROWS_PAD (ROWS + 128)     /* padding so A-tile overreads stay in-bounds */

#define META_COUNTS 0             /* [8]  per-expert token counts   */
#define META_CURSOR 8             /* [8]  gather cursors            */
#define META_OFFSET 16            /* [8]  segment start offsets     */
#define META_TOP2   32            /* [T]  packed e1 | e2<<4         */
#define META_ROWPOS (32 + T_TOKENS) /* [2T] token -> packed row ids */
#define META_INTS   (META_ROWPOS + 2 * T_TOKENS)

typedef __attribute__((ext_vector_type(8))) short short8;
typedef __attribute__((ext_vector_type(4))) float f32x4;
typedef __attribute__((ext_vector_type(4))) unsigned short u16x4;

__device__ __forceinline__ unsigned short bf16bits(float f) {
  unsigned u = __builtin_bit_cast(unsigned, f);
  u += 0x7fffu + ((u >> 16) & 1u);   // RNE (finite inputs only)
  return (unsigned short)(u >> 16);
}

__device__ __forceinline__ void gl_lds16(const void* g, void* l) {
  __builtin_amdgcn_global_load_lds(
      (const __attribute__((address_space(1))) unsigned int*)g,
      (__attribute__((address_space(3))) unsigned int*)l, 16, 0, 0);
}

// ---------------- weight transpose+convert: in [E][R][C] f32 -> out [E][C][R] bf16
__global__ __launch_bounds__(256) void transpose_w_kernel(
    const float* __restrict__ in, unsigned short* __restrict__ out, int R, int C) {
  __shared__ float tile[32][33];
  const int e = blockIdx.z;
  const int r0 = blockIdx.y * 32, c0 = blockIdx.x * 32;
  const float* inp = in + (size_t)e * R * C;
  unsigned short* outp = out + (size_t)e * R * C;
  const int tr = threadIdx.x >> 5, tc = threadIdx.x & 31;
#pragma unroll
  for (int s = 0; s < 32; s += 8)
    tile[tr + s][tc] = inp[(size_t)(r0 + tr + s) * C + (c0 + tc)];
  __syncthreads();
#pragma unroll
  for (int s = 0; s < 32; s += 8)
    outp[(size_t)(c0 + tr + s) * R + (r0 + tc)] = bf16bits(tile[tc][tr + s]);
}

// ---------------- router: one wave per token, fp64 accumulation, top-2 selection
__global__ __launch_bounds__(256) void router_kernel(
    const float* __restrict__ x, const float* __restrict__ rw,
    const float* __restrict__ rb, int* __restrict__ meta) {
  const int w = threadIdx.x >> 6;
  const int l = threadIdx.x & 63;
  const int t = blockIdx.x * 4 + w;
  const float* xr = x + (size_t)t * DIM + l * 16;
  double acc[8];
#pragma unroll
  for (int e = 0; e < 8; ++e) acc[e] = 0.0;
#pragma unroll
  for (int m = 0; m < 16; m += 4) {
    f32x4 xv = *(const f32x4*)(xr + m);
#pragma unroll
    for (int q = 0; q < 4; ++q) {
      double xs = (double)xv[q];
      const float* rwr = rw + (size_t)(l * 16 + m + q) * NEXP;
      f32x4 r0 = *(const f32x4*)rwr;
      f32x4 r1 = *(const f32x4*)(rwr + 4);
      acc[0] += xs * (double)r0[0]; acc[1] += xs * (double)r0[1];
      acc[2] += xs * (double)r0[2]; acc[3] += xs * (double)r0[3];
      acc[4] += xs * (double)r1[0]; acc[5] += xs * (double)r1[1];
      acc[6] += xs * (double)r1[2]; acc[7] += xs * (double)r1[3];
    }
  }
#pragma unroll
  for (int off = 32; off >= 1; off >>= 1) {
#pragma unroll
    for (int e = 0; e < 8; ++e) acc[e] += __shfl_down(acc[e], off);
  }
  if (l == 0) {
    double lg[8];
#pragma unroll
    for (int e = 0; e < 8; ++e) lg[e] = acc[e] + (double)rb[e];
    int e1 = 0; double b1v = lg[0];
#pragma unroll
    for (int e = 1; e < 8; ++e) if (lg[e] > b1v) { b1v = lg[e]; e1 = e; }
    int e2 = -1; double b2v = -1e300;
#pragma unroll
    for (int e = 0; e < 8; ++e) if (e != e1 && lg[e] > b2v) { b2v = lg[e]; e2 = e; }
    meta[META_TOP2 + t] = e1 | (e2 << 4);
    atomicAdd(&meta[META_COUNTS + e1], 1);
    atomicAdd(&meta[META_COUNTS + e2], 1);
  }
}

// ---------------- tiny prefix scan over 8 experts
__global__ void scan_kernel(int* meta) {
  if (threadIdx.x == 0 && blockIdx.x == 0) {
    int off = 0;
    for (int e = 0; e < 8; ++e) { meta[META_OFFSET + e] = off; off += meta[META_COUNTS + e]; }
  }
}

// ---------------- gather x rows (fp32 -> bf16) into packed per-expert segments
__global__ __launch_bounds__(256) void gather_kernel(
    const float* __restrict__ x, unsigned short* __restrict__ gx, int* __restrict__ meta) {
  __shared__ int sr[2];
  const int t = blockIdx.x;
  if (threadIdx.x == 0) {
    int p = meta[META_TOP2 + t];
    int e1 = p & 15, e2 = (p >> 4) & 15;
    int r1 = meta[META_OFFSET + e1] + atomicAdd(&meta[META_CURSOR + e1], 1);
    int r2 = meta[META_OFFSET + e2] + atomicAdd(&meta[META_CURSOR + e2], 1);
    meta[META_ROWPOS + 2 * t] = r1;
    meta[META_ROWPOS + 2 * t + 1] = r2;
    sr[0] = r1; sr[1] = r2;
  }
  __syncthreads();
  const int r1 = sr[0], r2 = sr[1];
  const int i = threadIdx.x * 4;
  f32x4 v = *(const f32x4*)(x + (size_t)t * DIM + i);
  u16x4 u;
  u[0] = bf16bits(v[0]); u[1] = bf16bits(v[1]);
  u[2] = bf16bits(v[2]); u[3] = bf16bits(v[3]);
  *(u16x4*)(gx + (size_t)r1 * DIM + i) = u;
  *(u16x4*)(gx + (size_t)r2 * DIM + i) = u;
}

// ---------------- grouped GEMM: C[row, n] = act(A[row, :] @ Bt[e][n, :] + bias[e][n])
// A: packed bf16 rows [ROWS_PAD][K]; Bt: bf16 [E][N][K]; expert segment from meta.
// 128x128 tile, BK=64, 4 waves, 16x16x32 MFMA, global_load_lds w/ XOR-swizzle (T2, rule #21).
template <int ACT>
__global__ __launch_bounds__(256) void moe_gemm(
    const unsigned short* __restrict__ A, const unsigned short* __restrict__ Bt,
    const float* __restrict__ bias, void* __restrict__ C,
    const int* __restrict__ meta, int K, int N) {
  const int e = blockIdx.z;
  const int n_e = meta[META_COUNTS + e];
  const int mt = blockIdx.y;
  if (mt * 128 >= n_e) return;
  const int n0 = blockIdx.x * 128;
  const int row0 = meta[META_OFFSET + e] + mt * 128;
  const int mrem = n_e - mt * 128;

  __shared__ __align__(16) unsigned short As[128 * 64];
  __shared__ __align__(16) unsigned short Bs[128 * 64];

  const int tid = threadIdx.x;
  const int w = tid >> 6, l = tid & 63;
  const int wr = w >> 1, wc = w & 1;

  f32x4 acc[4][4] = {};

  const unsigned short* Bte = Bt + (size_t)e * N * K;

  for (int kt = 0; kt < K; kt += 64) {
    // stage A tile (128x64) — LDS linear, global source inverse-swizzled
#pragma unroll
    for (int it = 0; it < 4; ++it) {
      int idx = it * 2048 + tid * 8;
      int row = idx >> 6;
      int cp = (idx >> 3) & 7;
      int col = ((cp ^ (row & 7)) << 3);
      gl_lds16(A + (size_t)(row0 + row) * K + kt + col, &As[it * 2048 + w * 512]);
    }
    // stage B tile (128 n-rows x 64 k)
#pragma unroll
    for (int it = 0; it < 4; ++it) {
      int idx = it * 2048 + tid * 8;
      int row = idx >> 6;
      int cp = (idx >> 3) & 7;
      int col = ((cp ^ (row & 7)) << 3);
      gl_lds16(Bte + (size_t)(n0 + row) * K + kt + col, &Bs[it * 2048 + w * 512]);
    }
    __syncthreads();
#pragma unroll
    for (int ks = 0; ks < 2; ++ks) {
      short8 av[4], bv[4];
#pragma unroll
      for (int i = 0; i < 4; ++i) {
        int r = wr * 64 + i * 16 + (l & 15);
        int c = ks * 4 + (l >> 4);
        av[i] = *(const short8*)&As[r * 64 + ((c ^ (r & 7)) << 3)];
      }
#pragma unroll
      for (int j = 0; j < 4; ++j) {
        int r = wc * 64 + j * 16 + (l & 15);
        int c = ks * 4 + (l >> 4);
        bv[j] = *(const short8*)&Bs[r * 64 + ((c ^ (r & 7)) << 3)];
      }
#pragma unroll
      for (int i = 0; i < 4; ++i)
#pragma unroll
        for (int j = 0; j < 4; ++j)
          acc[i][j] = __builtin_amdgcn_mfma_f32_16x16x32_bf16(av[i], bv[j], acc[i][j], 0, 0, 0);
    }
    __syncthreads();
  }

  // epilogue: C/D layout col = l&15, row = (l>>4)*4 + r
  const int lc = l & 15;
  const int lro = (l >> 4) << 2;
#pragma unroll
  for (int i = 0; i < 4; ++i) {
#pragma unroll
    for (int j = 0; j < 4; ++j) {
      int gn = n0 + wc * 64 + j * 16 + lc;
      float bz = bias[(size_t)e * N + gn];
#pragma unroll
      for (int r = 0; r < 4; ++r) {
        int lr = wr * 64 + i * 16 + lro + r;
        if (lr < mrem) {
          float v = acc[i][j][r] + bz;
          size_t off = (size_t)(row0 + lr) * N + gn;
          if (ACT == 1) {
            v = 0.5f * v * (1.0f + erff(v * 0.70710678118654752f));
            ((unsigned short*)C)[off] = bf16bits(v);
          } else {
            ((float*)C)[off] = v;
          }
        }
      }
    }
  }
}

// ---------------- combine: out[t] = y[r1] + y[r2]
__global__ __launch_bounds__(256) void combine_kernel(
    const float* __restrict__ y, const int* __restrict__ meta, float* __restrict__ out) {
  const int t = blockIdx.x;
  const int r1 = meta[META_ROWPOS + 2 * t];
  const int r2 = meta[META_ROWPOS + 2 * t + 1];
  const int i = threadIdx.x * 4;
  f32x4 a = *(const f32x4*)(y + (size_t)r1 * DIM + i);
  f32x4 b = *(const f32x4*)(y + (size_t)r2 * DIM + i);
  f32x4 o = a + b;
  *(f32x4*)(out + (size_t)t * DIM + i) = o;
}

extern "C" void kernel_launch(void* const* d_in, const int* in_sizes, int n_in,
                              void* d_out, int out_size, void* d_ws, size_t ws_size,
                              hipStream_t stream) {
  const float* x  = (const float*)d_in[0];
  const float* rw = (const float*)d_in[1];
  const float* rb = (const float*)d_in[2];
  const float* w1 = (const float*)d_in[3];
  const float* b1 = (const float*)d_in[4];
  const float* w2 = (const float*)d_in[5];
  const float* b2 = (const float*)d_in[6];
  float* out = (float*)d_out;

  char* p = (char*)d_ws;
  unsigned short* w1t = (unsigned short*)p; p += (size_t)NEXP * DIM * HID * 2;   // 64 MB
  unsigned short* w2t = (unsigned short*)p; p += (size_t)NEXP * DIM * HID * 2;   // 64 MB
  unsigned short* gx  = (unsigned short*)p; p += (size_t)ROWS_PAD * DIM * 2;     // 32 MB
  unsigned short* h   = (unsigned short*)p; p += (size_t)ROWS_PAD * HID * 2;     // 129 MB
  float*          y   = (float*)p;          p += (size_t)ROWS_PAD * DIM * 4;     // 64 MB
  int*            meta = (int*)p;                                                // ~96 KB
  (void)in_sizes; (void)n_in; (void)out_size; (void)ws_size;

  hipMemsetAsync(meta, 0, 64, stream);  // counts + cursors

  // w1 [E][D][H] -> w1t [E][H][D] ; w2 [E][H][D] -> w2t [E][D][H]
  transpose_w_kernel<<<dim3(HID / 32, DIM / 32, NEXP), 256, 0, stream>>>(w1, w1t, DIM, HID);
  transpose_w_kernel<<<dim3(DIM / 32, HID / 32, NEXP), 256, 0, stream>>>(w2, w2t, HID, DIM);

  router_kernel<<<T_TOKENS / 4, 256, 0, stream>>>(x, rw, rb, meta);
  scan_kernel<<<1, 64, 0, stream>>>(meta);
  gather_kernel<<<T_TOKENS, 256, 0, stream>>>(x, gx, meta);

  // GEMM1: [n_e,1024] @ [1024,4096] + b1, gelu -> h (bf16)
  moe_gemm<1><<<dim3(HID / 128, 64, NEXP), 256, 0, stream>>>(gx, w1t, b1, h, meta, DIM, HID);
  // GEMM2: [n_e,4096] @ [4096,1024] + b2 -> y (f32)
  moe_gemm<0><<<dim3(DIM / 128, 64, NEXP), 256, 0, stream>>>(h, w2t, b2, y, meta, HID, DIM);

  combine_kernel<<<T_TOKENS, 256, 0, stream>>>(y, meta, out);
}

// Round 2
// 610.001 us; speedup vs baseline: 2.3487x; 2.3487x over previous
//
#include <hip/hip_runtime.h>

#define T_TOKENS 8192
#define DIM 1024
#define NEXP 8
#define HID 4096
#define ROWS (2 * T_TOKENS)       /* 16384 packed (token,expert) rows */
#define ROWS_PAD (ROWS + 128)     /* padding so A-tile overreads stay in-bounds */

#define META_COUNTS 0             /* [8]  per-expert token counts   */
#define META_OFFSET 16            /* [8]  segment start offsets     */
#define META_TOP2   32            /* [T]  packed e1 | e2<<4         */
#define META_ROWPOS (32 + T_TOKENS) /* [2T] token -> packed row ids */

typedef __attribute__((ext_vector_type(8))) short short8;
typedef __attribute__((ext_vector_type(4))) float f32x4;
typedef __attribute__((ext_vector_type(4))) unsigned short u16x4;

__device__ __forceinline__ unsigned short bf16bits(float f) {
  unsigned u = __builtin_bit_cast(unsigned, f);
  u += 0x7fffu + ((u >> 16) & 1u);   // RNE (finite inputs only)
  return (unsigned short)(u >> 16);
}

__device__ __forceinline__ void gl_lds16(const void* g, void* l) {
  __builtin_amdgcn_global_load_lds(
      (const __attribute__((address_space(1))) unsigned int*)g,
      (__attribute__((address_space(3))) unsigned int*)l, 16, 0, 0);
}

// ---------------- weight transpose+convert: in [E][R][C] f32 -> out [E][C][R] bf16
__global__ __launch_bounds__(256) void transpose_w_kernel(
    const float* __restrict__ in, unsigned short* __restrict__ out, int R, int C) {
  __shared__ float tile[32][33];
  const int e = blockIdx.z;
  const int r0 = blockIdx.y * 32, c0 = blockIdx.x * 32;
  const float* inp = in + (size_t)e * R * C;
  unsigned short* outp = out + (size_t)e * R * C;
  const int tr = threadIdx.x >> 5, tc = threadIdx.x & 31;
#pragma unroll
  for (int s = 0; s < 32; s += 8)
    tile[tr + s][tc] = inp[(size_t)(r0 + tr + s) * C + (c0 + tc)];
  __syncthreads();
#pragma unroll
  for (int s = 0; s < 32; s += 8)
    outp[(size_t)(c0 + tr + s) * R + (r0 + tc)] = bf16bits(tile[tc][tr + s]);
}

// ---------------- router: one wave per token, fp64 accumulation, top-2 selection
__global__ __launch_bounds__(256) void router_kernel(
    const float* __restrict__ x, const float* __restrict__ rw,
    const float* __restrict__ rb, int* __restrict__ meta) {
  const int w = threadIdx.x >> 6;
  const int l = threadIdx.x & 63;
  const int t = blockIdx.x * 4 + w;
  const float* xr = x + (size_t)t * DIM + l * 16;
  double acc[8];
#pragma unroll
  for (int e = 0; e < 8; ++e) acc[e] = 0.0;
#pragma unroll
  for (int m = 0; m < 16; m += 4) {
    f32x4 xv = *(const f32x4*)(xr + m);
#pragma unroll
    for (int q = 0; q < 4; ++q) {
      double xs = (double)xv[q];
      const float* rwr = rw + (size_t)(l * 16 + m + q) * NEXP;
      f32x4 r0 = *(const f32x4*)rwr;
      f32x4 r1 = *(const f32x4*)(rwr + 4);
      acc[0] += xs * (double)r0[0]; acc[1] += xs * (double)r0[1];
      acc[2] += xs * (double)r0[2]; acc[3] += xs * (double)r0[3];
      acc[4] += xs * (double)r1[0]; acc[5] += xs * (double)r1[1];
      acc[6] += xs * (double)r1[2]; acc[7] += xs * (double)r1[3];
    }
  }
#pragma unroll
  for (int off = 32; off >= 1; off >>= 1) {
#pragma unroll
    for (int e = 0; e < 8; ++e) acc[e] += __shfl_down(acc[e], off);
  }
  if (l == 0) {
    double lg[8];
#pragma unroll
    for (int e = 0; e < 8; ++e) lg[e] = acc[e] + (double)rb[e];
    int e1 = 0; double b1v = lg[0];
#pragma unroll
    for (int e = 1; e < 8; ++e) if (lg[e] > b1v) { b1v = lg[e]; e1 = e; }
    int e2 = -1; double b2v = -1e300;
#pragma unroll
    for (int e = 0; e < 8; ++e) if (e != e1 && lg[e] > b2v) { b2v = lg[e]; e2 = e; }
    meta[META_TOP2 + t] = e1 | (e2 << 4);
  }
}

// ---------------- assign: deterministic block-scan replacement for atomics.
// One 1024-thread block; each thread owns 8 consecutive tokens.
__global__ __launch_bounds__(1024) void assign_kernel(int* __restrict__ meta) {
  __shared__ int hist[NEXP][1024];
  __shared__ int own[NEXP][1024];
  const int tid = threadIdx.x;
#pragma unroll
  for (int e = 0; e < NEXP; ++e) { hist[e][tid] = 0; own[e][tid] = 0; }
  __syncthreads();
  int top2[8];
#pragma unroll
  for (int q = 0; q < 8; ++q) {
    int t = tid * 8 + q;
    int p = meta[META_TOP2 + t];
    top2[q] = p;
    hist[p & 15][tid] += 1;
    hist[(p >> 4) & 15][tid] += 1;
  }
#pragma unroll
  for (int e = 0; e < NEXP; ++e) own[e][tid] = hist[e][tid];
  __syncthreads();
  // Hillis-Steele inclusive scan over tid, all 8 experts per pass
  for (int off = 1; off < 1024; off <<= 1) {
    int add[NEXP];
#pragma unroll
    for (int e = 0; e < NEXP; ++e) add[e] = (tid >= off) ? hist[e][tid - off] : 0;
    __syncthreads();
#pragma unroll
    for (int e = 0; e < NEXP; ++e) hist[e][tid] += add[e];
    __syncthreads();
  }
  int offp[NEXP];
  {
    int o = 0;
#pragma unroll
    for (int e = 0; e < NEXP; ++e) {
      offp[e] = o;
      o += hist[e][1023];
    }
  }
  if (tid == 0) {
#pragma unroll
    for (int e = 0; e < NEXP; ++e) {
      meta[META_COUNTS + e] = hist[e][1023];
      meta[META_OFFSET + e] = offp[e];
    }
  }
  // turn own[] into this thread's running cursor per expert
#pragma unroll
  for (int e = 0; e < NEXP; ++e) own[e][tid] = offp[e] + hist[e][tid] - own[e][tid];
#pragma unroll
  for (int q = 0; q < 8; ++q) {
    int t = tid * 8 + q;
    int p = top2[q];
    int e1 = p & 15, e2 = (p >> 4) & 15;
    int r1 = own[e1][tid]; own[e1][tid] = r1 + 1;
    int r2 = own[e2][tid]; own[e2][tid] = r2 + 1;
    meta[META_ROWPOS + 2 * t] = r1;
    meta[META_ROWPOS + 2 * t + 1] = r2;
  }
}

// ---------------- gather x rows (fp32 -> bf16) into packed per-expert segments
__global__ __launch_bounds__(256) void gather_kernel(
    const float* __restrict__ x, unsigned short* __restrict__ gx,
    const int* __restrict__ meta) {
  const int t = blockIdx.x;
  const int r1 = meta[META_ROWPOS + 2 * t];
  const int r2 = meta[META_ROWPOS + 2 * t + 1];
  const int i = threadIdx.x * 4;
  f32x4 v = *(const f32x4*)(x + (size_t)t * DIM + i);
  u16x4 u;
  u[0] = bf16bits(v[0]); u[1] = bf16bits(v[1]);
  u[2] = bf16bits(v[2]); u[3] = bf16bits(v[3]);
  *(u16x4*)(gx + (size_t)r1 * DIM + i) = u;
  *(u16x4*)(gx + (size_t)r2 * DIM + i) = u;
}

// ---------------- grouped GEMM: C[row, n] = act(A[row, :] @ Bt[e][n, :] + bias[e][n])
// A: packed bf16 rows [ROWS_PAD][K]; Bt: bf16 [E][N][K]; expert segment from meta.
// 128x128 tile, BK=64, 4 waves, 16x16x32 MFMA, global_load_lds w/ XOR-swizzle (T2, rule #21).
template <int ACT>
__global__ __launch_bounds__(256) void moe_gemm(
    const unsigned short* __restrict__ A, const unsigned short* __restrict__ Bt,
    const float* __restrict__ bias, void* __restrict__ C,
    const int* __restrict__ meta, int K, int N) {
  const int e = blockIdx.z;
  const int n_e = meta[META_COUNTS + e];
  const int mt = blockIdx.y;
  if (mt * 128 >= n_e) return;
  const int n0 = blockIdx.x * 128;
  const int row0 = meta[META_OFFSET + e] + mt * 128;
  const int mrem = n_e - mt * 128;

  __shared__ __align__(16) unsigned short As[128 * 64];
  __shared__ __align__(16) unsigned short Bs[128 * 64];

  const int tid = threadIdx.x;
  const int w = tid >> 6, l = tid & 63;
  const int wr = w >> 1, wc = w & 1;

  f32x4 acc[4][4] = {};

  const unsigned short* Bte = Bt + (size_t)e * N * K;

  for (int kt = 0; kt < K; kt += 64) {
    // stage A tile (128x64) — LDS linear, global source inverse-swizzled
#pragma unroll
    for (int it = 0; it < 4; ++it) {
      int idx = it * 2048 + tid * 8;
      int row = idx >> 6;
      int cp = (idx >> 3) & 7;
      int col = ((cp ^ (row & 7)) << 3);
      gl_lds16(A + (size_t)(row0 + row) * K + kt + col, &As[it * 2048 + w * 512]);
    }
    // stage B tile (128 n-rows x 64 k)
#pragma unroll
    for (int it = 0; it < 4; ++it) {
      int idx = it * 2048 + tid * 8;
      int row = idx >> 6;
      int cp = (idx >> 3) & 7;
      int col = ((cp ^ (row & 7)) << 3);
      gl_lds16(Bte + (size_t)(n0 + row) * K + kt + col, &Bs[it * 2048 + w * 512]);
    }
    __syncthreads();
#pragma unroll
    for (int ks = 0; ks < 2; ++ks) {
      short8 av[4], bv[4];
#pragma unroll
      for (int i = 0; i < 4; ++i) {
        int r = wr * 64 + i * 16 + (l & 15);
        int c = ks * 4 + (l >> 4);
        av[i] = *(const short8*)&As[r * 64 + ((c ^ (r & 7)) << 3)];
      }
#pragma unroll
      for (int j = 0; j < 4; ++j) {
        int r = wc * 64 + j * 16 + (l & 15);
        int c = ks * 4 + (l >> 4);
        bv[j] = *(const short8*)&Bs[r * 64 + ((c ^ (r & 7)) << 3)];
      }
#pragma unroll
      for (int i = 0; i < 4; ++i)
#pragma unroll
        for (int j = 0; j < 4; ++j)
          acc[i][j] = __builtin_amdgcn_mfma_f32_16x16x32_bf16(av[i], bv[j], acc[i][j], 0, 0, 0);
    }
    __syncthreads();
  }

  // epilogue: C/D layout col = l&15, row = (l>>4)*4 + r
  const int lc = l & 15;
  const int lro = (l >> 4) << 2;
#pragma unroll
  for (int i = 0; i < 4; ++i) {
#pragma unroll
    for (int j = 0; j < 4; ++j) {
      int gn = n0 + wc * 64 + j * 16 + lc;
      float bz = bias[(size_t)e * N + gn];
#pragma unroll
      for (int r = 0; r < 4; ++r) {
        int lr = wr * 64 + i * 16 + lro + r;
        if (lr < mrem) {
          float v = acc[i][j][r] + bz;
          size_t off = (size_t)(row0 + lr) * N + gn;
          if (ACT == 1) {
            v = 0.5f * v * (1.0f + erff(v * 0.70710678118654752f));
            ((unsigned short*)C)[off] = bf16bits(v);
          } else {
            ((float*)C)[off] = v;
          }
        }
      }
    }
  }
}

// ---------------- combine: out[t] = y[r1] + y[r2]
__global__ __launch_bounds__(256) void combine_kernel(
    const float* __restrict__ y, const int* __restrict__ meta, float* __restrict__ out) {
  const int t = blockIdx.x;
  const int r1 = meta[META_ROWPOS + 2 * t];
  const int r2 = meta[META_ROWPOS + 2 * t + 1];
  const int i = threadIdx.x * 4;
  f32x4 a = *(const f32x4*)(y + (size_t)r1 * DIM + i);
  f32x4 b = *(const f32x4*)(y + (size_t)r2 * DIM + i);
  f32x4 o = a + b;
  *(f32x4*)(out + (size_t)t * DIM + i) = o;
}

extern "C" void kernel_launch(void* const* d_in, const int* in_sizes, int n_in,
                              void* d_out, int out_size, void* d_ws, size_t ws_size,
                              hipStream_t stream) {
  const float* x  = (const float*)d_in[0];
  const float* rw = (const float*)d_in[1];
  const float* rb = (const float*)d_in[2];
  const float* w1 = (const float*)d_in[3];
  const float* b1 = (const float*)d_in[4];
  const float* w2 = (const float*)d_in[5];
  const float* b2 = (const float*)d_in[6];
  float* out = (float*)d_out;

  char* p = (char*)d_ws;
  unsigned short* w1t = (unsigned short*)p; p += (size_t)NEXP * DIM * HID * 2;   // 64 MB
  unsigned short* w2t = (unsigned short*)p; p += (size_t)NEXP * DIM * HID * 2;   // 64 MB
  unsigned short* gx  = (unsigned short*)p; p += (size_t)ROWS_PAD * DIM * 2;     // 32 MB
  unsigned short* h   = (unsigned short*)p; p += (size_t)ROWS_PAD * HID * 2;     // 129 MB
  float*          y   = (float*)p;          p += (size_t)ROWS_PAD * DIM * 4;     // 64 MB
  int*            meta = (int*)p;                                                // ~96 KB
  (void)in_sizes; (void)n_in; (void)out_size; (void)ws_size;

  // w1 [E][D][H] -> w1t [E][H][D] ; w2 [E][H][D] -> w2t [E][D][H]
  transpose_w_kernel<<<dim3(HID / 32, DIM / 32, NEXP), 256, 0, stream>>>(w1, w1t, DIM, HID);
  transpose_w_kernel<<<dim3(DIM / 32, HID / 32, NEXP), 256, 0, stream>>>(w2, w2t, HID, DIM);

  router_kernel<<<T_TOKENS / 4, 256, 0, stream>>>(x, rw, rb, meta);
  assign_kernel<<<1, 1024, 0, stream>>>(meta);
  gather_kernel<<<T_TOKENS, 256, 0, stream>>>(x, gx, meta);

  // GEMM1: [n_e,1024] @ [1024,4096] + b1, gelu -> h (bf16)
  moe_gemm<1><<<dim3(HID / 128, 64, NEXP), 256, 0, stream>>>(gx, w1t, b1, h, meta, DIM, HID);
  // GEMM2: [n_e,4096] @ [4096,1024] + b2 -> y (f32)
  moe_gemm<0><<<dim3(DIM / 128, 64, NEXP), 256, 0, stream>>>(h, w2t, b2, y, meta, HID, DIM);

  combine_kernel<<<T_TOKENS, 256, 0, stream>>>(y, meta, out);
}